// Round 1
// baseline (342.893 us; speedup 1.0000x reference)
//
#include <hip/hip_runtime.h>
#include <math.h>

// HierarchicalPooling collapsed pipeline.
// N=32768 nodes, D=256, S=4 scales, H=8 heads, DH=32, CS=3276, C=11 clusters.

namespace {
constexpr int N  = 32768;
constexpr int D  = 256;
constexpr int CS = 3276;
constexpr int SHN = 32;           // S*H
constexpr int KD_CPC = 52;        // 64-node chunks per full cluster
constexpr int KD_NB  = KD_CPC*10 + 1;   // 521 blocks

// ws layout (float offsets)
constexpr size_t WQ_OFF   = 0;                               // 32*256
constexpr size_t CQ_OFF   = WQ_OFF + 8192;                   // 32
constexpr size_t SC_OFF   = CQ_OFF + 32;                     // N*32 scores->weights (in-place)
constexpr size_t PART_OFF = SC_OFF + (size_t)N*SHN;          // 521*8192
constexpr size_t XW_OFF   = PART_OFF + (size_t)KD_NB*8192;   // 11*8192
constexpr size_t CF2_OFF  = XW_OFF + (size_t)11*8192;        // 11*256
}

// ---- KA: wq[sh][d] = scale * sum_j Wk[s][d][h*32+j]*pq[s][h][j];  cq[sh] likewise from bk.
__global__ __launch_bounds__(256) void ka(const float* __restrict__ Wk, const float* __restrict__ bk,
                                          const float* __restrict__ pq, float* __restrict__ ws){
  int b = blockIdx.x, t = threadIdx.x;
  const float scale = 0.17677669529663688f;   // 32^-0.5
  if (b < 32){
    int s = b >> 3, h = b & 7;
    const float* wrow = Wk + ((size_t)s<<16) + (size_t)t*256 + h*32;
    const float* q = pq + (s*8 + h)*32;
    float a = 0.f;
#pragma unroll
    for (int j=0;j<32;j++) a = fmaf(wrow[j], q[j], a);
    ws[WQ_OFF + (size_t)b*256 + t] = a*scale;
  } else if (t < 32){
    int s = t >> 3, h = t & 7;
    const float* br = bk + s*256 + h*32;
    const float* q = pq + t*32;
    float a = 0.f;
#pragma unroll
    for (int j=0;j<32;j++) a = fmaf(br[j], q[j], a);
    ws[CQ_OFF + t] = a*scale;
  }
}

// ---- KB: scores[n][sh] = x[n,:]@wq[sh,:] + cq[sh].  Block = 64 nodes.
// thread: sh = t&31 (output), dg = t>>5 (d-slice of 32). wq slice lives in 8 float4 regs.
__global__ __launch_bounds__(256) void kb(const float* __restrict__ x, float* __restrict__ ws){
  int t = threadIdx.x;
  int sh = t & 31, dg = t >> 5;
  int n0 = blockIdx.x * 64;
  const float4* WQ4 = (const float4*)(ws + WQ_OFF);
  float4 wq[8];
#pragma unroll
  for (int q=0;q<8;q++) wq[q] = WQ4[sh*64 + dg*8 + q];
  float cqr = ws[CQ_OFF + sh];
  float* sc = ws + SC_OFF;
  __shared__ float red[8*288];   // [8 nodes][32 sh][9 pad]
  const float4* X4 = (const float4*)x;
  for (int r=0;r<8;r++){
    int nb = n0 + r*8;
    float p[8];
#pragma unroll
    for (int jn=0;jn<8;jn++){
      const float4* xr = X4 + (size_t)(nb+jn)*64 + dg*8;
      float a = 0.f;
#pragma unroll
      for (int q=0;q<8;q++){
        float4 xv = xr[q];
        a = fmaf(xv.x, wq[q].x, a); a = fmaf(xv.y, wq[q].y, a);
        a = fmaf(xv.z, wq[q].z, a); a = fmaf(xv.w, wq[q].w, a);
      }
      p[jn] = a;
    }
#pragma unroll
    for (int jn=0;jn<8;jn++) red[jn*288 + sh*9 + dg] = p[jn];
    __syncthreads();
    {
      int jn = t >> 5, s2 = t & 31;
      float v = 0.f;
#pragma unroll
      for (int g2=0; g2<8; g2++) v += red[jn*288 + s2*9 + g2];
      sc[(size_t)(nb+jn)*SHN + s2] = v + cqr;
    }
    __syncthreads();
  }
}

// ---- KC: per-cluster softmax over nodes, in-place scores -> weights. 11 blocks.
__global__ __launch_bounds__(256) void kc(float* __restrict__ ws){
  int c = blockIdx.x, t = threadIdx.x;
  int sh = t & 31, g = t >> 5;
  int n0 = c*CS, n1 = min(n0+CS, N);
  float* sc = ws + SC_OFF;
  __shared__ float wred[128];
  __shared__ float sm[32], rd[32];
  float m = -3.0e38f;
  for (int n = n0+g; n < n1; n += 8) m = fmaxf(m, sc[(size_t)n*SHN + sh]);
  m = fmaxf(m, __shfl_xor(m, 32, 64));
  int wid = t >> 6, lane = t & 63;
  if (lane < 32) wred[wid*32 + sh] = m;
  __syncthreads();
  if (t < 32) sm[t] = fmaxf(fmaxf(wred[t], wred[32+t]), fmaxf(wred[64+t], wred[96+t]));
  __syncthreads();
  float mx = sm[sh];
  float ssum = 0.f;
  for (int n = n0+g; n < n1; n += 8) ssum += __expf(sc[(size_t)n*SHN + sh] - mx);
  ssum += __shfl_xor(ssum, 32, 64);
  if (lane < 32) wred[wid*32 + sh] = ssum;
  __syncthreads();
  if (t < 32) rd[t] = 1.0f/(wred[t]+wred[32+t]+wred[64+t]+wred[96+t]);
  __syncthreads();
  float rden = rd[sh];
  for (int n = n0+g; n < n1; n += 8){
    size_t i = (size_t)n*SHN + sh;
    sc[i] = __expf(sc[i] - mx)*rden;
  }
}

// ---- KD: xw partials. Block = one 64-node chunk inside one cluster.
// thread owns d = t; acc[32] over sh in registers; w row via broadcast float4 loads.
__global__ __launch_bounds__(256) void kd(const float* __restrict__ x, float* __restrict__ ws){
  int b = blockIdx.x, t = threadIdx.x;
  int c  = (b < 520) ? (b / KD_CPC) : 10;
  int wi = (b < 520) ? (b % KD_CPC) : 0;
  int n0 = c*CS + wi*64;
  int n1 = min(n0 + 64, min((c+1)*CS, N));
  const float* wgt = ws + SC_OFF;
  float acc[32];
#pragma unroll
  for (int j=0;j<32;j++) acc[j] = 0.f;
  for (int n=n0; n<n1; ++n){
    float xv = x[(size_t)n*D + t];
    const float4* W4 = (const float4*)(wgt + (size_t)n*SHN);
    float wv[32];
#pragma unroll
    for (int q=0;q<8;q++){ float4 w = W4[q]; wv[4*q]=w.x; wv[4*q+1]=w.y; wv[4*q+2]=w.z; wv[4*q+3]=w.w; }
#pragma unroll
    for (int j=0;j<32;j++) acc[j] = fmaf(wv[j], xv, acc[j]);
  }
  float* pr = ws + PART_OFF + (size_t)b*8192;
#pragma unroll
  for (int j=0;j<32;j++) pr[j*256 + t] = acc[j];
}

// ---- KE: reduce chunk partials -> xw[c][sh][d]. 352 blocks * 256 = 90112 elems.
__global__ __launch_bounds__(256) void ke(float* __restrict__ ws){
  int e = blockIdx.x*256 + threadIdx.x;   // 0..90111
  int c = e >> 13, r = e & 8191;
  int nch = (c < 10) ? KD_CPC : 1;
  int cb = c*KD_CPC;
  const float* part = ws + PART_OFF;
  float a = 0.f;
  for (int k=0;k<nch;k++) a += part[(size_t)(cb+k)*8192 + r];
  ws[XW_OFF + e] = a;
}

// ---- KCL: per-cluster pipeline: pooled -> out -> Wf1 -> LN -> GELU -> Wf2. 11 blocks.
__global__ __launch_bounds__(256) void kcl(float* __restrict__ ws,
    const float* __restrict__ Wv, const float* __restrict__ bv,
    const float* __restrict__ Wo, const float* __restrict__ bo,
    const float* __restrict__ Wf1, const float* __restrict__ bf1,
    const float* __restrict__ lng, const float* __restrict__ lnb,
    const float* __restrict__ Wf2, const float* __restrict__ bf2){
  int c = blockIdx.x, t = threadIdx.x;
  __shared__ float xwl[32*260];   // padded stride 260 -> conflict-free head broadcasts
  __shared__ float pl[4*260];
  __shared__ float ol[1024];
  __shared__ float hl[256];
  __shared__ float rs1[4], rs2[4];
  const float* xwc = ws + XW_OFF + (size_t)c*8192;
  for (int k=t; k<8192; k+=256) xwl[(k>>8)*260 + (k&255)] = xwc[k];
  __syncthreads();
  float rcnt = (c < 10) ? (1.0f/(float)CS) : 0.125f;
  int s = t >> 6, e64 = t & 63, h = e64 >> 3;
  // stage A: pooled[s][e4..e4+3] = (sum_d Wv[s,d,e]*xw[s*8+h][d] + bv)*rcnt
  float4 a = make_float4(0.f,0.f,0.f,0.f);
  const float4* WV4 = (const float4*)Wv;
  const float* xr = xwl + (s*8+h)*260;
#pragma unroll 8
  for (int d=0; d<256; ++d){
    float4 w = WV4[s*16384 + d*64 + e64];
    float xv = xr[d];
    a.x=fmaf(w.x,xv,a.x); a.y=fmaf(w.y,xv,a.y); a.z=fmaf(w.z,xv,a.z); a.w=fmaf(w.w,xv,a.w);
  }
  float4 bvv = ((const float4*)bv)[s*64 + e64];
  a.x=(a.x+bvv.x)*rcnt; a.y=(a.y+bvv.y)*rcnt; a.z=(a.z+bvv.z)*rcnt; a.w=(a.w+bvv.w)*rcnt;
  ((float4*)pl)[s*65 + e64] = a;
  __syncthreads();
  // stage B: out[s][e2] = sum_d pooled[s][d]*Wo[s,d,e2] + bo
  float4 o = make_float4(0.f,0.f,0.f,0.f);
  const float4* WO4 = (const float4*)Wo;
  const float* pr = pl + s*260;
#pragma unroll 8
  for (int d=0; d<256; ++d){
    float4 w = WO4[s*16384 + d*64 + e64];
    float pv = pr[d];
    o.x=fmaf(w.x,pv,o.x); o.y=fmaf(w.y,pv,o.y); o.z=fmaf(w.z,pv,o.z); o.w=fmaf(w.w,pv,o.w);
  }
  float4 bov = ((const float4*)bo)[s*64 + e64];
  o.x+=bov.x; o.y+=bov.y; o.z+=bov.z; o.w+=bov.w;
  ((float4*)ol)[t] = o;
  __syncthreads();
  // stage C: h[f=t] = sum_k ol[k]*Wf1[k][f] + bf1
  float hacc = 0.f;
#pragma unroll 8
  for (int k=0;k<1024;k++) hacc = fmaf(ol[k], Wf1[(size_t)k*256 + t], hacc);
  hacc += bf1[t];
  // LayerNorm over 256
  float s1 = hacc, s2v = hacc*hacc;
  for (int off=32; off>0; off>>=1){ s1 += __shfl_down(s1, off, 64); s2v += __shfl_down(s2v, off, 64); }
  int wid = t>>6, lane = t&63;
  if (lane==0){ rs1[wid]=s1; rs2[wid]=s2v; }
  __syncthreads();
  float S1 = rs1[0]+rs1[1]+rs1[2]+rs1[3];
  float S2 = rs2[0]+rs2[1]+rs2[2]+rs2[3];
  float mu = S1*(1.0f/256.0f);
  float var = S2*(1.0f/256.0f) - mu*mu;
  float rsig = rsqrtf(var + 1e-5f);
  float hn = (hacc - mu)*rsig*lng[t] + lnb[t];
  float ge = 0.5f*hn*(1.0f + erff(hn*0.70710678118654752f));   // exact GELU
  hl[t] = ge;
  __syncthreads();
  // stage D: f2[g=t] = sum_f hl[f]*Wf2[f][g] + bf2
  float oa = 0.f;
#pragma unroll 8
  for (int f=0;f<256;f++) oa = fmaf(hl[f], Wf2[(size_t)f*256 + t], oa);
  ws[CF2_OFF + (size_t)c*256 + t] = oa + bf2[t];
}

// ---- KBC: broadcast cluster rows to all nodes. 8192 blocks * 256 threads = N*64 float4s.
__global__ __launch_bounds__(256) void kbc(const float* __restrict__ ws, float4* __restrict__ out){
  unsigned idx = blockIdx.x*256u + threadIdx.x;
  unsigned n = idx >> 6, q = idx & 63u;
  unsigned c = n / (unsigned)CS;
  out[idx] = ((const float4*)(ws + CF2_OFF))[c*64u + q];
}

extern "C" void kernel_launch(void* const* d_in, const int* in_sizes, int n_in,
                              void* d_out, int out_size, void* d_ws, size_t ws_size,
                              hipStream_t stream) {
  const float* x   = (const float*)d_in[0];
  // d_in[1] edge_index, d_in[2] batch: unused by the reference computation
  const float* Wk  = (const float*)d_in[3];
  const float* bk  = (const float*)d_in[4];
  const float* Wv  = (const float*)d_in[5];
  const float* bv  = (const float*)d_in[6];
  const float* Wo  = (const float*)d_in[7];
  const float* bo  = (const float*)d_in[8];
  const float* pq  = (const float*)d_in[9];
  const float* Wf1 = (const float*)d_in[10];
  const float* bf1 = (const float*)d_in[11];
  const float* lng = (const float*)d_in[12];
  const float* lnb = (const float*)d_in[13];
  const float* Wf2 = (const float*)d_in[14];
  const float* bf2 = (const float*)d_in[15];
  float* ws = (float*)d_ws;
  float4* out = (float4*)d_out;

  hipLaunchKernelGGL(ka,  dim3(33),   dim3(256), 0, stream, Wk, bk, pq, ws);
  hipLaunchKernelGGL(kb,  dim3(512),  dim3(256), 0, stream, x, ws);
  hipLaunchKernelGGL(kc,  dim3(11),   dim3(256), 0, stream, ws);
  hipLaunchKernelGGL(kd,  dim3(521),  dim3(256), 0, stream, x, ws);
  hipLaunchKernelGGL(ke,  dim3(352),  dim3(256), 0, stream, ws);
  hipLaunchKernelGGL(kcl, dim3(11),   dim3(256), 0, stream, ws, Wv, bv, Wo, bo, Wf1, bf1, lng, lnb, Wf2, bf2);
  hipLaunchKernelGGL(kbc, dim3(8192), dim3(256), 0, stream, ws, out);
}

// Round 2
// 162.706 us; speedup vs baseline: 2.1074x; 2.1074x over previous
//
#include <hip/hip_runtime.h>
#include <math.h>

// HierarchicalPooling collapsed pipeline, round 2.
// N=32768, D=256, S=4, H=8, DH=32, CS=3276, C=11.
// Round-1 lesson: 11-block kernels (kc, kcl) are latency-exposed disasters.
// This round: two-level softmax reduction, on-the-fly weights in kd,
// cluster pipeline split into wide split-k kernels.

namespace {
constexpr int N   = 32768;
constexpr int D   = 256;
constexpr int CS  = 3276;
constexpr int CPN = 128;               // nodes per chunk
constexpr int CPC = 26;                // chunks per full cluster (26*128 >= 3276)
constexpr int NB  = CPC*10 + 1;        // 261 chunk blocks

// ws layout (float offsets)
constexpr size_t WQ_OFF  = 0;                                // 32*256
constexpr size_t CQ_OFF  = WQ_OFF + 8192;                    // 32
constexpr size_t SC_OFF  = CQ_OFF + 32;                      // N*32 raw scores
constexpr size_t PART_OFF= SC_OFF + (size_t)N*32;            // 261*8192
constexpr size_t XW_OFF  = PART_OFF + (size_t)NB*8192;       // 11*8192
constexpr size_t PM_OFF  = XW_OFF + 11*8192;                 // 261*32 chunk max
constexpr size_t PS_OFF  = PM_OFF + (size_t)NB*32;           // 261*32 chunk sumexp
constexpr size_t MX_OFF  = PS_OFF + (size_t)NB*32;           // 11*32 cluster max
constexpr size_t RD_OFF  = MX_OFF + 352;                     // 11*32 1/denom
constexpr size_t OL_OFF  = RD_OFF + 352;                     // 11*1024 out rows
constexpr size_t HP_OFF  = OL_OFF + 11264;                   // 11*4*256 Wf1 partials
constexpr size_t HL_OFF  = HP_OFF + 11264;                   // 11*256 gelu(h)
constexpr size_t FP_OFF  = HL_OFF + 2816;                    // 11*4*256 Wf2 partials
constexpr size_t CF2_OFF = FP_OFF + 11264;                   // 11*256 final rows
}

// ---- KA: wq[sh][d] = scale * <Wk[s][d][h*32..], q[s][h]>, cq[sh] from bk.
__global__ __launch_bounds__(256) void ka(const float* __restrict__ Wk, const float* __restrict__ bk,
                                          const float* __restrict__ pq, float* __restrict__ ws){
  int b = blockIdx.x, t = threadIdx.x;
  const float scale = 0.17677669529663688f;   // 32^-0.5
  if (b < 32){
    int s = b >> 3, h = b & 7;
    const float* wrow = Wk + ((size_t)s<<16) + (size_t)t*256 + h*32;
    const float* q = pq + (s*8 + h)*32;
    float a = 0.f;
#pragma unroll
    for (int j=0;j<32;j++) a = fmaf(wrow[j], q[j], a);
    ws[WQ_OFF + (size_t)b*256 + t] = a*scale;
  } else if (t < 32){
    int s = t >> 3, h = t & 7;
    const float* br = bk + s*256 + h*32;
    const float* q = pq + t*32;
    float a = 0.f;
#pragma unroll
    for (int j=0;j<32;j++) a = fmaf(br[j], q[j], a);
    ws[CQ_OFF + t] = a*scale;
  }
}

// ---- KB: scores[n][sh] = x[n,:]@wq[sh,:] + cq[sh].  Block = 64 nodes.
__global__ __launch_bounds__(256) void kb(const float* __restrict__ x, float* __restrict__ ws){
  int t = threadIdx.x;
  int sh = t & 31, dg = t >> 5;
  int n0 = blockIdx.x * 64;
  const float4* WQ4 = (const float4*)(ws + WQ_OFF);
  float4 wq[8];
#pragma unroll
  for (int q=0;q<8;q++) wq[q] = WQ4[sh*64 + dg*8 + q];
  float cqr = ws[CQ_OFF + sh];
  float* sc = ws + SC_OFF;
  __shared__ float red[8*288];   // [8 nodes][32 sh][9 pad]
  const float4* X4 = (const float4*)x;
  for (int r=0;r<8;r++){
    int nb = n0 + r*8;
    float p[8];
#pragma unroll
    for (int jn=0;jn<8;jn++){
      const float4* xr = X4 + (size_t)(nb+jn)*64 + dg*8;
      float a = 0.f;
#pragma unroll
      for (int q=0;q<8;q++){
        float4 xv = xr[q];
        a = fmaf(xv.x, wq[q].x, a); a = fmaf(xv.y, wq[q].y, a);
        a = fmaf(xv.z, wq[q].z, a); a = fmaf(xv.w, wq[q].w, a);
      }
      p[jn] = a;
    }
#pragma unroll
    for (int jn=0;jn<8;jn++) red[jn*288 + sh*9 + dg] = p[jn];
    __syncthreads();
    {
      int jn = t >> 5, s2 = t & 31;
      float v = 0.f;
#pragma unroll
      for (int g2=0; g2<8; g2++) v += red[jn*288 + s2*9 + g2];
      sc[(size_t)(nb+jn)*32 + s2] = v + cqr;
    }
    __syncthreads();
  }
}

// ---- KC1: per-chunk max & sumexp partials. 261 blocks.
__global__ __launch_bounds__(256) void kc1(float* __restrict__ ws){
  int b = blockIdx.x, t = threadIdx.x;
  int c  = (b < 260) ? (b / CPC) : 10;
  int wi = (b < 260) ? (b % CPC) : 0;
  int n0 = c*CS + wi*CPN;
  int n1 = min(n0 + CPN, min((c+1)*CS, N));
  int sh = t & 31, g = t >> 5;
  const float* sc = ws + SC_OFF;
  __shared__ float red[8*33];
  __shared__ float sm[32];
  float m = -3.0e38f;
  for (int n = n0+g; n < n1; n += 8) m = fmaxf(m, sc[(size_t)n*32 + sh]);
  red[g*33 + sh] = m;
  __syncthreads();
  if (t < 32){
    float mm = red[t];
#pragma unroll
    for (int g2=1; g2<8; g2++) mm = fmaxf(mm, red[g2*33 + t]);
    sm[t] = mm;
  }
  __syncthreads();
  float M = sm[sh];
  float s = 0.f;
  for (int n = n0+g; n < n1; n += 8) s += __expf(sc[(size_t)n*32 + sh] - M);
  red[g*33 + sh] = s;
  __syncthreads();
  if (t < 32){
    float ss = red[t];
#pragma unroll
    for (int g2=1; g2<8; g2++) ss += red[g2*33 + t];
    ws[PM_OFF + (size_t)b*32 + t] = sm[t];
    ws[PS_OFF + (size_t)b*32 + t] = ss;
  }
}

// ---- KC2: combine chunk partials -> mx[c][sh], rden[c][sh]. 11 blocks x 1 wave.
__global__ __launch_bounds__(64) void kc2(float* __restrict__ ws){
  int c = blockIdx.x, t = threadIdx.x;
  if (t >= 32) return;
  int cb  = (c < 10) ? c*CPC : 260;
  int nch = (c < 10) ? CPC : 1;
  const float* pm = ws + PM_OFF;
  const float* ps = ws + PS_OFF;
  float M = -3.0e38f;
  for (int k=0;k<nch;k++) M = fmaxf(M, pm[(size_t)(cb+k)*32 + t]);
  float S = 0.f;
  for (int k=0;k<nch;k++) S += ps[(size_t)(cb+k)*32 + t] * __expf(pm[(size_t)(cb+k)*32 + t] - M);
  ws[MX_OFF + (size_t)c*32 + t] = M;
  ws[RD_OFF + (size_t)c*32 + t] = 1.0f/S;
}

// ---- KD: xw partials with on-the-fly weights. Block = 128-node chunk.
__global__ __launch_bounds__(256) void kd(const float* __restrict__ x, float* __restrict__ ws){
  int b = blockIdx.x, t = threadIdx.x;
  int c  = (b < 260) ? (b / CPC) : 10;
  int wi = (b < 260) ? (b % CPC) : 0;
  int n0 = c*CS + wi*CPN;
  int n1 = min(n0 + CPN, min((c+1)*CS, N));
  int cnt = n1 - n0;
  __shared__ float wl[128*32];   // 16 KB weight tile
  {
    int j = t >> 1, sh0 = (t & 1)*16;
    if (j < cnt){
      const float* scp = ws + SC_OFF + (size_t)(n0+j)*32 + sh0;
      const float* mxp = ws + MX_OFF + (size_t)c*32 + sh0;
      const float* rdp = ws + RD_OFF + (size_t)c*32 + sh0;
      float* dst = wl + j*32 + sh0;
#pragma unroll
      for (int i=0;i<16;i++)
        dst[i] = __expf(scp[i] - mxp[i]) * rdp[i];
    }
  }
  __syncthreads();
  float acc[32];
#pragma unroll
  for (int j=0;j<32;j++) acc[j] = 0.f;
  for (int j=0;j<cnt;++j){
    float xv = x[(size_t)(n0+j)*D + t];
    const float4* W4 = (const float4*)(wl + j*32);
#pragma unroll
    for (int q=0;q<8;q++){
      float4 w = W4[q];
      acc[4*q  ] = fmaf(w.x, xv, acc[4*q  ]);
      acc[4*q+1] = fmaf(w.y, xv, acc[4*q+1]);
      acc[4*q+2] = fmaf(w.z, xv, acc[4*q+2]);
      acc[4*q+3] = fmaf(w.w, xv, acc[4*q+3]);
    }
  }
  float* pr = ws + PART_OFF + (size_t)b*8192;
#pragma unroll
  for (int j=0;j<32;j++) pr[j*256 + t] = acc[j];
}

// ---- KE: reduce chunk partials -> xw[c][sh][d]. 352 blocks.
__global__ __launch_bounds__(256) void ke(float* __restrict__ ws){
  int e = blockIdx.x*256 + threadIdx.x;   // 0..90111
  int c = e >> 13, r = e & 8191;
  int nch = (c < 10) ? CPC : 1;
  int cb  = (c < 10) ? c*CPC : 260;
  const float* part = ws + PART_OFF;
  float a = 0.f;
  for (int k=0;k<nch;k++) a += part[(size_t)(cb+k)*8192 + r];
  ws[XW_OFF + e] = a;
}

// ---- KAB: pooled -> out per (c,s). 44 blocks x 512 threads (split-d).
__global__ __launch_bounds__(512) void kab(float* __restrict__ ws,
    const float* __restrict__ Wv, const float* __restrict__ bv,
    const float* __restrict__ Wo, const float* __restrict__ bo){
  int b = blockIdx.x; int c = b >> 2, s = b & 3; int t = threadIdx.x;
  __shared__ float xwl[8*264];
  __shared__ float redl[2*264];
  __shared__ float pl[264];
  const float* xwc = ws + XW_OFF + (size_t)c*8192 + (size_t)s*2048;
  {
    int k = t*4;                      // 512 threads * 4 = 2048 floats
    float4 v = *(const float4*)(xwc + k);
    *(float4*)(xwl + (k>>8)*264 + (k&255)) = v;
  }
  __syncthreads();
  int ep = t & 255, dh = t >> 8;
  int h = ep >> 5;
  float rcnt = (c < 10) ? (1.0f/(float)CS) : 0.125f;
  {
    float a = 0.f;
    const float* wv = Wv + (size_t)s*65536 + (size_t)dh*128*256 + ep;
    const float* xr = xwl + h*264 + dh*128;
#pragma unroll 8
    for (int d=0; d<128; ++d) a = fmaf(wv[(size_t)d*256], xr[d], a);
    redl[dh*264 + ep] = a;
  }
  __syncthreads();
  if (t < 256) pl[t] = (redl[t] + redl[264+t] + bv[s*256+t]) * rcnt;
  __syncthreads();
  {
    float o = 0.f;
    const float* wo = Wo + (size_t)s*65536 + (size_t)dh*128*256 + ep;
    const float* pr2 = pl + dh*128;
#pragma unroll 8
    for (int d=0; d<128; ++d) o = fmaf(wo[(size_t)d*256], pr2[d], o);
    redl[dh*264 + ep] = o;
  }
  __syncthreads();
  if (t < 256) ws[OL_OFF + (size_t)c*1024 + s*256 + t] = redl[t] + redl[264+t] + bo[s*256+t];
}

// ---- KF1: h partials, split-k over 4 quarters of 1024. 44 blocks.
__global__ __launch_bounds__(256) void kf1(const float* __restrict__ Wf1, float* __restrict__ ws){
  int b = blockIdx.x; int c = b >> 2, kq = b & 3; int t = threadIdx.x;
  __shared__ float oll[256];
  oll[t] = ws[OL_OFF + (size_t)c*1024 + kq*256 + t];
  __syncthreads();
  float a = 0.f;
  const float* wf = Wf1 + (size_t)(kq*256)*256 + t;
#pragma unroll 8
  for (int k=0;k<256;k++) a = fmaf(oll[k], wf[(size_t)k*256], a);
  ws[HP_OFF + (size_t)(c*4+kq)*256 + t] = a;
}

// ---- KLN: combine partials + bias -> LayerNorm -> GELU. 11 blocks.
__global__ __launch_bounds__(256) void kln(float* __restrict__ ws, const float* __restrict__ bf1,
    const float* __restrict__ lng, const float* __restrict__ lnb){
  int c = blockIdx.x, t = threadIdx.x;
  __shared__ float rs1[4], rs2[4];
  float hacc = bf1[t];
#pragma unroll
  for (int q=0;q<4;q++) hacc += ws[HP_OFF + (size_t)(c*4+q)*256 + t];
  float s1 = hacc, s2v = hacc*hacc;
  for (int off=32; off>0; off>>=1){ s1 += __shfl_down(s1, off, 64); s2v += __shfl_down(s2v, off, 64); }
  int wid = t>>6, lane = t&63;
  if (lane==0){ rs1[wid]=s1; rs2[wid]=s2v; }
  __syncthreads();
  float S1 = rs1[0]+rs1[1]+rs1[2]+rs1[3];
  float S2 = rs2[0]+rs2[1]+rs2[2]+rs2[3];
  float mu = S1*(1.0f/256.0f);
  float var = S2*(1.0f/256.0f) - mu*mu;
  float rsig = rsqrtf(var + 1e-5f);
  float hn = (hacc - mu)*rsig*lng[t] + lnb[t];
  float ge = 0.5f*hn*(1.0f + erff(hn*0.70710678118654752f));   // exact GELU
  ws[HL_OFF + (size_t)c*256 + t] = ge;
}

// ---- KF2: f2 partials, split-k over 4 quarters of 256. 44 blocks.
__global__ __launch_bounds__(256) void kf2(const float* __restrict__ Wf2, float* __restrict__ ws){
  int b = blockIdx.x; int c = b >> 2, fq = b & 3; int t = threadIdx.x;
  __shared__ float hll[64];
  if (t < 64) hll[t] = ws[HL_OFF + (size_t)c*256 + fq*64 + t];
  __syncthreads();
  float a = 0.f;
  const float* wf = Wf2 + (size_t)(fq*64)*256 + t;
#pragma unroll 8
  for (int f=0;f<64;f++) a = fmaf(hll[f], wf[(size_t)f*256], a);
  ws[FP_OFF + (size_t)(c*4+fq)*256 + t] = a;
}

// ---- KF3: combine f2 partials + bf2 -> cf2 rows. 11 blocks.
__global__ __launch_bounds__(256) void kf3(float* __restrict__ ws, const float* __restrict__ bf2){
  int c = blockIdx.x, t = threadIdx.x;
  float a = bf2[t];
#pragma unroll
  for (int q=0;q<4;q++) a += ws[FP_OFF + (size_t)(c*4+q)*256 + t];
  ws[CF2_OFF + (size_t)c*256 + t] = a;
}

// ---- KBC: broadcast cluster rows to all nodes. 8192 blocks.
__global__ __launch_bounds__(256) void kbc(const float* __restrict__ ws, float4* __restrict__ out){
  unsigned idx = blockIdx.x*256u + threadIdx.x;
  unsigned n = idx >> 6, q = idx & 63u;
  unsigned c = n / (unsigned)CS;
  out[idx] = ((const float4*)(ws + CF2_OFF))[c*64u + q];
}

extern "C" void kernel_launch(void* const* d_in, const int* in_sizes, int n_in,
                              void* d_out, int out_size, void* d_ws, size_t ws_size,
                              hipStream_t stream) {
  const float* x   = (const float*)d_in[0];
  // d_in[1] edge_index, d_in[2] batch: unused by the reference computation
  const float* Wk  = (const float*)d_in[3];
  const float* bk  = (const float*)d_in[4];
  const float* Wv  = (const float*)d_in[5];
  const float* bv  = (const float*)d_in[6];
  const float* Wo  = (const float*)d_in[7];
  const float* bo  = (const float*)d_in[8];
  const float* pq  = (const float*)d_in[9];
  const float* Wf1 = (const float*)d_in[10];
  const float* bf1 = (const float*)d_in[11];
  const float* lng = (const float*)d_in[12];
  const float* lnb = (const float*)d_in[13];
  const float* Wf2 = (const float*)d_in[14];
  const float* bf2 = (const float*)d_in[15];
  float* ws = (float*)d_ws;
  float4* out = (float4*)d_out;

  hipLaunchKernelGGL(ka,  dim3(33),   dim3(256), 0, stream, Wk, bk, pq, ws);
  hipLaunchKernelGGL(kb,  dim3(512),  dim3(256), 0, stream, x, ws);
  hipLaunchKernelGGL(kc1, dim3(NB),   dim3(256), 0, stream, ws);
  hipLaunchKernelGGL(kc2, dim3(11),   dim3(64),  0, stream, ws);
  hipLaunchKernelGGL(kd,  dim3(NB),   dim3(256), 0, stream, x, ws);
  hipLaunchKernelGGL(ke,  dim3(352),  dim3(256), 0, stream, ws);
  hipLaunchKernelGGL(kab, dim3(44),   dim3(512), 0, stream, ws, Wv, bv, Wo, bo);
  hipLaunchKernelGGL(kf1, dim3(44),   dim3(256), 0, stream, Wf1, ws);
  hipLaunchKernelGGL(kln, dim3(11),   dim3(256), 0, stream, ws, bf1, lng, lnb);
  hipLaunchKernelGGL(kf2, dim3(44),   dim3(256), 0, stream, Wf2, ws);
  hipLaunchKernelGGL(kf3, dim3(11),   dim3(256), 0, stream, ws, bf2);
  hipLaunchKernelGGL(kbc, dim3(8192), dim3(256), 0, stream, ws, out);
}

// Round 4
// 153.603 us; speedup vs baseline: 2.2323x; 1.0593x over previous
//
#include <hip/hip_runtime.h>
#include <math.h>

// HierarchicalPooling collapsed pipeline, round 4 (= R3 + one-line fix).
// N=32768, D=256, S=4, H=8, DH=32, CS=3276, C=11.
// R3 bug: pass-1 LDS read used byte offset (dg*128) in float-pointer math;
// correct slice offset is dg*32 floats. Scores were garbage for dg>=2.

namespace {
constexpr int N   = 32768;
constexpr int D   = 256;
constexpr int CS  = 3276;
constexpr int CPN = 64;                // nodes per chunk
constexpr int CPC = 52;                // chunks per full cluster
constexpr int NB  = CPC*10 + 1;        // 521 chunk blocks

// ws layout (float offsets)
constexpr size_t WQ_OFF  = 0;                                // 32*256
constexpr size_t CQ_OFF  = WQ_OFF + 8192;                    // 32
constexpr size_t PART_OFF= CQ_OFF + 32;                      // NB*8192 chunk xw partials
constexpr size_t XW_OFF  = PART_OFF + (size_t)NB*8192;       // 11*8192
constexpr size_t PM_OFF  = XW_OFF + 11*8192;                 // NB*32 chunk max
constexpr size_t PS_OFF  = PM_OFF + (size_t)NB*32;           // NB*32 chunk sumexp
constexpr size_t MX_OFF  = PS_OFF + (size_t)NB*32;           // 11*32 cluster max
constexpr size_t RD_OFF  = MX_OFF + 352;                     // 11*32 1/denom
constexpr size_t OL_OFF  = RD_OFF + 352;                     // 11*1024 out rows
constexpr size_t HP_OFF  = OL_OFF + 11264;                   // 11*4*256 Wf1 partials
constexpr size_t HL_OFF  = HP_OFF + 11264;                   // 11*256 gelu(h)
constexpr size_t FP_OFF  = HL_OFF + 2816;                    // 11*4*256 Wf2 partials
constexpr size_t CF2_OFF = FP_OFF + 11264;                   // 11*256 final rows
}

// ---- KA: wq[sh][d] = scale * <Wk[s][d][h*32..], q[s][h]>, cq[sh] from bk.
__global__ __launch_bounds__(256) void ka(const float* __restrict__ Wk, const float* __restrict__ bk,
                                          const float* __restrict__ pq, float* __restrict__ ws){
  int b = blockIdx.x, t = threadIdx.x;
  const float scale = 0.17677669529663688f;   // 32^-0.5
  if (b < 32){
    int s = b >> 3, h = b & 7;
    const float* wrow = Wk + ((size_t)s<<16) + (size_t)t*256 + h*32;
    const float* q = pq + (s*8 + h)*32;
    float a = 0.f;
#pragma unroll
    for (int j=0;j<32;j++) a = fmaf(wrow[j], q[j], a);
    ws[WQ_OFF + (size_t)b*256 + t] = a*scale;
  } else if (t < 32){
    int s = t >> 3, h = t & 7;
    const float* br = bk + s*256 + h*32;
    const float* q = pq + t*32;
    float a = 0.f;
#pragma unroll
    for (int j=0;j<32;j++) a = fmaf(br[j], q[j], a);
    ws[CQ_OFF + t] = a*scale;
  }
}

// ---- KBD: fused scores + chunk softmax partials + chunk xw partials.
// Block = one 64-node cluster-aligned chunk, 256 threads.
__global__ __launch_bounds__(256) void kbd(const float* __restrict__ x, float* __restrict__ ws){
  int b = blockIdx.x, t = threadIdx.x;
  int c  = (b < 520) ? (b / CPC) : 10;
  int wi = (b < 520) ? (b % CPC) : 0;
  int n0 = c*CS + wi*CPN;
  int n1 = min(n0 + CPN, min((c+1)*CS, N));
  int cnt = n1 - n0;                       // 64, 12 (cluster-9 tail), or 8 (cluster 10)
  int nst = (cnt > 32) ? 2 : 1;

  __shared__ float xt[32*260];    // 32-node x subtile, padded rows
  __shared__ float red[32*132];   // [j][sh*4+wave] d-slice partials
  __shared__ float scl[64*33];    // scores [j][sh]
  __shared__ float wl[64*36];     // exp-weights [j][sh], 144B row stride
  __shared__ float redm[8*33];
  __shared__ float msh[32];

  int sh = t & 31, dg = t >> 5;
  float4 wq[8];
  const float4* WQ4 = (const float4*)(ws + WQ_OFF);
#pragma unroll
  for (int q=0;q<8;q++) wq[q] = WQ4[sh*64 + dg*8 + q];
  float cqr = ws[CQ_OFF + sh];
  const float4* X4 = (const float4*)x;

  // ---- pass 1: scores (LDS-staged, coalesced global loads)
  for (int st=0; st<nst; ++st){
    __syncthreads();
#pragma unroll
    for (int k=0;k<8;k++){
      int f = t + k*256;                 // 0..2047
      int j = f >> 6, c4 = f & 63;
      int n = n0 + st*32 + j;
      float4 v = (n < n1) ? X4[(size_t)n*64 + c4] : make_float4(0.f,0.f,0.f,0.f);
      *(float4*)(xt + j*260 + c4*4) = v;
    }
    __syncthreads();
    for (int j=0;j<32;++j){
      const float4* xr = (const float4*)(xt + j*260 + dg*32);   // dg slice = 32 floats (R3 bug: was dg*128)
      float a = 0.f;
#pragma unroll
      for (int q=0;q<8;q++){
        float4 xv = xr[q];
        a = fmaf(xv.x, wq[q].x, a); a = fmaf(xv.y, wq[q].y, a);
        a = fmaf(xv.z, wq[q].z, a); a = fmaf(xv.w, wq[q].w, a);
      }
      a += __shfl_xor(a, 32, 64);        // combine dg pair within wave
      if ((t & 32) == 0) red[j*132 + sh*4 + (t>>6)] = a;
    }
    __syncthreads();
    {
      int jj = t >> 5;                   // 0..7
#pragma unroll
      for (int r=0;r<4;r++){
        int j = jj + r*8;
        float4 v = *(const float4*)(red + j*132 + sh*4);
        scl[(st*32 + j)*33 + sh] = v.x+v.y+v.z+v.w + cqr;
      }
    }
  }
  __syncthreads();

  // ---- chunk softmax partials (max & sumexp), masked to j<cnt
  int jg = t >> 5;
  float m = -3.0e38f;
#pragma unroll
  for (int r=0;r<8;r++){
    int j = jg + r*8;
    if (j < cnt) m = fmaxf(m, scl[j*33 + sh]);
  }
  redm[jg*33 + sh] = m;
  __syncthreads();
  if (t < 32){
    float mm = redm[t];
#pragma unroll
    for (int g=1; g<8; g++) mm = fmaxf(mm, redm[g*33 + t]);
    msh[t] = mm;
  }
  __syncthreads();
  float M = msh[sh];
  float s = 0.f;
#pragma unroll
  for (int r=0;r<8;r++){
    int j = jg + r*8;
    if (j < cnt) s += __expf(scl[j*33 + sh] - M);
  }
  redm[jg*33 + sh] = s;
  __syncthreads();
  if (t < 32){
    float ss = redm[t];
#pragma unroll
    for (int g=1; g<8; g++) ss += redm[g*33 + t];
    ws[PM_OFF + (size_t)b*32 + t] = msh[t];
    ws[PS_OFF + (size_t)b*32 + t] = ss;
  }
  // exp-weights with chunk-local max (unnormalized; ke rescales)
#pragma unroll
  for (int r=0;r<8;r++){
    int j = jg + r*8;
    wl[j*36 + sh] = (j < cnt) ? __expf(scl[j*33 + sh] - M) : 0.f;
  }

  // ---- pass 2: xw chunk partials. Thread owns column t, acc over 32 sh.
  float acc[32];
#pragma unroll
  for (int q=0;q<32;q++) acc[q] = 0.f;
  for (int st=0; st<nst; ++st){
    __syncthreads();                      // xt reuse + wl visibility (st=0)
#pragma unroll
    for (int k=0;k<8;k++){
      int f = t + k*256;
      int j = f >> 6, c4 = f & 63;
      int n = n0 + st*32 + j;
      float4 v = (n < n1) ? X4[(size_t)n*64 + c4] : make_float4(0.f,0.f,0.f,0.f);
      *(float4*)(xt + j*260 + c4*4) = v;
    }
    __syncthreads();
    int lim = min(32, cnt - st*32);
    for (int j=0;j<lim;++j){
      float xv = xt[j*260 + t];
      const float4* W4 = (const float4*)(wl + (st*32+j)*36);
#pragma unroll
      for (int q=0;q<8;q++){
        float4 w = W4[q];
        acc[4*q  ] = fmaf(w.x, xv, acc[4*q  ]);
        acc[4*q+1] = fmaf(w.y, xv, acc[4*q+1]);
        acc[4*q+2] = fmaf(w.z, xv, acc[4*q+2]);
        acc[4*q+3] = fmaf(w.w, xv, acc[4*q+3]);
      }
    }
  }
  float* pr = ws + PART_OFF + (size_t)b*8192;
#pragma unroll
  for (int q=0;q<32;q++) pr[q*256 + t] = acc[q];
}

// ---- KC2: combine chunk partials -> mx[c][sh], rden[c][sh]. 11 blocks x 1 wave.
__global__ __launch_bounds__(64) void kc2(float* __restrict__ ws){
  int c = blockIdx.x, t = threadIdx.x;
  if (t >= 32) return;
  int cb  = (c < 10) ? c*CPC : 520;
  int nch = (c < 10) ? CPC : 1;
  const float* pm = ws + PM_OFF;
  const float* ps = ws + PS_OFF;
  float M = -3.0e38f;
  for (int k=0;k<nch;k++) M = fmaxf(M, pm[(size_t)(cb+k)*32 + t]);
  float S = 0.f;
  for (int k=0;k<nch;k++) S += ps[(size_t)(cb+k)*32 + t] * __expf(pm[(size_t)(cb+k)*32 + t] - M);
  ws[MX_OFF + (size_t)c*32 + t] = M;
  ws[RD_OFF + (size_t)c*32 + t] = 1.0f/S;
}

// ---- KE: rescaled reduce of chunk partials -> normalized xw[c][sh][d]. 352 blocks.
__global__ __launch_bounds__(256) void ke(float* __restrict__ ws){
  int e = blockIdx.x*256 + threadIdx.x;   // 0..90111
  int c = e >> 13, r = e & 8191;
  int sh = r >> 8;
  int nch = (c < 10) ? CPC : 1;
  int cb  = (c < 10) ? c*CPC : 520;
  float M    = ws[MX_OFF + (size_t)c*32 + sh];
  float rden = ws[RD_OFF + (size_t)c*32 + sh];
  const float* part = ws + PART_OFF;
  const float* pm   = ws + PM_OFF;
  float a = 0.f;
  for (int k=0;k<nch;k++){
    float f = __expf(pm[(size_t)(cb+k)*32 + sh] - M);
    a = fmaf(part[(size_t)(cb+k)*8192 + r], f, a);
  }
  ws[XW_OFF + e] = a * rden;
}

// ---- KAB: pooled -> out per (c,s). 44 blocks x 512 threads (split-d).
__global__ __launch_bounds__(512) void kab(float* __restrict__ ws,
    const float* __restrict__ Wv, const float* __restrict__ bv,
    const float* __restrict__ Wo, const float* __restrict__ bo){
  int b = blockIdx.x; int c = b >> 2, s = b & 3; int t = threadIdx.x;
  __shared__ float xwl[8*264];
  __shared__ float redl[2*264];
  __shared__ float pl[264];
  const float* xwc = ws + XW_OFF + (size_t)c*8192 + (size_t)s*2048;
  {
    int k = t*4;
    float4 v = *(const float4*)(xwc + k);
    *(float4*)(xwl + (k>>8)*264 + (k&255)) = v;
  }
  __syncthreads();
  int ep = t & 255, dh = t >> 8;
  int h = ep >> 5;
  float rcnt = (c < 10) ? (1.0f/(float)CS) : 0.125f;
  {
    float a = 0.f;
    const float* wv = Wv + (size_t)s*65536 + (size_t)dh*128*256 + ep;
    const float* xr = xwl + h*264 + dh*128;
#pragma unroll 8
    for (int d=0; d<128; ++d) a = fmaf(wv[(size_t)d*256], xr[d], a);
    redl[dh*264 + ep] = a;
  }
  __syncthreads();
  if (t < 256) pl[t] = (redl[t] + redl[264+t] + bv[s*256+t]) * rcnt;
  __syncthreads();
  {
    float o = 0.f;
    const float* wo = Wo + (size_t)s*65536 + (size_t)dh*128*256 + ep;
    const float* pr2 = pl + dh*128;
#pragma unroll 8
    for (int d=0; d<128; ++d) o = fmaf(wo[(size_t)d*256], pr2[d], o);
    redl[dh*264 + ep] = o;
  }
  __syncthreads();
  if (t < 256) ws[OL_OFF + (size_t)c*1024 + s*256 + t] = redl[t] + redl[264+t] + bo[s*256+t];
}

// ---- KF1: h partials, split-k over 4 quarters of 1024. 44 blocks.
__global__ __launch_bounds__(256) void kf1(const float* __restrict__ Wf1, float* __restrict__ ws){
  int b = blockIdx.x; int c = b >> 2, kq = b & 3; int t = threadIdx.x;
  __shared__ float oll[256];
  oll[t] = ws[OL_OFF + (size_t)c*1024 + kq*256 + t];
  __syncthreads();
  float a = 0.f;
  const float* wf = Wf1 + (size_t)(kq*256)*256 + t;
#pragma unroll 8
  for (int k=0;k<256;k++) a = fmaf(oll[k], wf[(size_t)k*256], a);
  ws[HP_OFF + (size_t)(c*4+kq)*256 + t] = a;
}

// ---- KLN: combine partials + bias -> LayerNorm -> GELU. 11 blocks.
__global__ __launch_bounds__(256) void kln(float* __restrict__ ws, const float* __restrict__ bf1,
    const float* __restrict__ lng, const float* __restrict__ lnb){
  int c = blockIdx.x, t = threadIdx.x;
  __shared__ float rs1[4], rs2[4];
  float hacc = bf1[t];
#pragma unroll
  for (int q=0;q<4;q++) hacc += ws[HP_OFF + (size_t)(c*4+q)*256 + t];
  float s1 = hacc, s2v = hacc*hacc;
  for (int off=32; off>0; off>>=1){ s1 += __shfl_down(s1, off, 64); s2v += __shfl_down(s2v, off, 64); }
  int wid = t>>6, lane = t&63;
  if (lane==0){ rs1[wid]=s1; rs2[wid]=s2v; }
  __syncthreads();
  float S1 = rs1[0]+rs1[1]+rs1[2]+rs1[3];
  float S2 = rs2[0]+rs2[1]+rs2[2]+rs2[3];
  float mu = S1*(1.0f/256.0f);
  float var = S2*(1.0f/256.0f) - mu*mu;
  float rsig = rsqrtf(var + 1e-5f);
  float hn = (hacc - mu)*rsig*lng[t] + lnb[t];
  float ge = 0.5f*hn*(1.0f + erff(hn*0.70710678118654752f));   // exact GELU
  ws[HL_OFF + (size_t)c*256 + t] = ge;
}

// ---- KF2: f2 partials, split-k over 4 quarters of 256. 44 blocks.
__global__ __launch_bounds__(256) void kf2(const float* __restrict__ Wf2, float* __restrict__ ws){
  int b = blockIdx.x; int c = b >> 2, fq = b & 3; int t = threadIdx.x;
  __shared__ float hll[64];
  if (t < 64) hll[t] = ws[HL_OFF + (size_t)c*256 + fq*64 + t];
  __syncthreads();
  float a = 0.f;
  const float* wf = Wf2 + (size_t)(fq*64)*256 + t;
#pragma unroll 8
  for (int f=0;f<64;f++) a = fmaf(hll[f], wf[(size_t)f*256], a);
  ws[FP_OFF + (size_t)(c*4+fq)*256 + t] = a;
}

// ---- KF3: combine f2 partials + bf2 -> cf2 rows. 11 blocks.
__global__ __launch_bounds__(256) void kf3(float* __restrict__ ws, const float* __restrict__ bf2){
  int c = blockIdx.x, t = threadIdx.x;
  float a = bf2[t];
#pragma unroll
  for (int q=0;q<4;q++) a += ws[FP_OFF + (size_t)(c*4+q)*256 + t];
  ws[CF2_OFF + (size_t)c*256 + t] = a;
}

// ---- KBC: broadcast cluster rows to all nodes. 8192 blocks.
__global__ __launch_bounds__(256) void kbc(const float* __restrict__ ws, float4* __restrict__ out){
  unsigned idx = blockIdx.x*256u + threadIdx.x;
  unsigned n = idx >> 6, q = idx & 63u;
  unsigned c = n / (unsigned)CS;
  out[idx] = ((const float4*)(ws + CF2_OFF))[c*64u + q];
}

extern "C" void kernel_launch(void* const* d_in, const int* in_sizes, int n_in,
                              void* d_out, int out_size, void* d_ws, size_t ws_size,
                              hipStream_t stream) {
  const float* x   = (const float*)d_in[0];
  // d_in[1] edge_index, d_in[2] batch: unused by the reference computation
  const float* Wk  = (const float*)d_in[3];
  const float* bk  = (const float*)d_in[4];
  const float* Wv  = (const float*)d_in[5];
  const float* bv  = (const float*)d_in[6];
  const float* Wo  = (const float*)d_in[7];
  const float* bo  = (const float*)d_in[8];
  const float* pq  = (const float*)d_in[9];
  const float* Wf1 = (const float*)d_in[10];
  const float* bf1 = (const float*)d_in[11];
  const float* lng = (const float*)d_in[12];
  const float* lnb = (const float*)d_in[13];
  const float* Wf2 = (const float*)d_in[14];
  const float* bf2 = (const float*)d_in[15];
  float* ws = (float*)d_ws;
  float4* out = (float4*)d_out;

  hipLaunchKernelGGL(ka,  dim3(33),   dim3(256), 0, stream, Wk, bk, pq, ws);
  hipLaunchKernelGGL(kbd, dim3(NB),   dim3(256), 0, stream, x, ws);
  hipLaunchKernelGGL(kc2, dim3(11),   dim3(64),  0, stream, ws);
  hipLaunchKernelGGL(ke,  dim3(352),  dim3(256), 0, stream, ws);
  hipLaunchKernelGGL(kab, dim3(44),   dim3(512), 0, stream, ws, Wv, bv, Wo, bo);
  hipLaunchKernelGGL(kf1, dim3(44),   dim3(256), 0, stream, Wf1, ws);
  hipLaunchKernelGGL(kln, dim3(11),   dim3(256), 0, stream, ws, bf1, lng, lnb);
  hipLaunchKernelGGL(kf2, dim3(44),   dim3(256), 0, stream, Wf2, ws);
  hipLaunchKernelGGL(kf3, dim3(11),   dim3(256), 0, stream, ws, bf2);
  hipLaunchKernelGGL(kbc, dim3(8192), dim3(256), 0, stream, ws, out);
}

// Round 5
// 102.861 us; speedup vs baseline: 3.3335x; 1.4933x over previous
//
#include <hip/hip_runtime.h>
#include <math.h>

// HierarchicalPooling collapsed pipeline, round 5.
// N=32768, D=256, S=4, H=8, DH=32, CS=3276, C=11.
// R4 lessons: kbd at 69KB LDS = 2 blocks/CU, latency-bound (VALU 17%, HBM 6%);
// x staged 4x; rest = 9 narrow kernels. R5: 16-node subtiles staged once with
// online-softmax rescale, in-wave shfl score reduction (no red[] array),
// LDS ~19.5KB + launch_bounds(256,4) -> 4 blocks/CU; widened small kernels.

namespace {
constexpr int N   = 32768;
constexpr int D   = 256;
constexpr int CS  = 3276;
constexpr int CPN = 64;                // nodes per kbd2 block
constexpr int CPC = 52;                // 64-node chunks per full cluster
constexpr int NB  = CPC*10 + 1;        // 521 blocks

// ws layout (float offsets); total ~4.45M floats = 17.8 MB
constexpr size_t WQ_OFF  = 0;                                // 32*256
constexpr size_t CQ_OFF  = WQ_OFF + 8192;                    // 32
constexpr size_t PART_OFF= CQ_OFF + 32;                      // NB*8192 chunk xw partials
constexpr size_t PM_OFF  = PART_OFF + (size_t)NB*8192;       // NB*32 chunk max
constexpr size_t PS_OFF  = PM_OFF + (size_t)NB*32;           // NB*32 chunk sumexp
constexpr size_t XW_OFF  = PS_OFF + (size_t)NB*32;           // 11*8192
constexpr size_t PL_OFF  = XW_OFF + 11*8192;                 // 11*1024 pooled
constexpr size_t OL_OFF  = PL_OFF + 11264;                   // 11*1024 out rows
constexpr size_t HP_OFF  = OL_OFF + 11264;                   // 11*4*256 Wf1 partials
constexpr size_t HL_OFF  = HP_OFF + 11264;                   // 11*256 gelu(h)
constexpr size_t FP_OFF  = HL_OFF + 2816;                    // 11*4*256 Wf2 partials
}

// ---- KA: wq[sh][d] = scale * <Wk[s][d][h*32..], q[s][h]>, cq[sh] from bk.
__global__ __launch_bounds__(256) void ka(const float* __restrict__ Wk, const float* __restrict__ bk,
                                          const float* __restrict__ pq, float* __restrict__ ws){
  int b = blockIdx.x, t = threadIdx.x;
  const float scale = 0.17677669529663688f;   // 32^-0.5
  if (b < 32){
    int s = b >> 3, h = b & 7;
    const float* wrow = Wk + ((size_t)s<<16) + (size_t)t*256 + h*32;
    const float* q = pq + (s*8 + h)*32;
    float a = 0.f;
#pragma unroll
    for (int j=0;j<32;j++) a = fmaf(wrow[j], q[j], a);
    ws[WQ_OFF + (size_t)b*256 + t] = a*scale;
  } else if (t < 32){
    int s = t >> 3, h = t & 7;
    const float* br = bk + s*256 + h*32;
    const float* q = pq + t*32;
    float a = 0.f;
#pragma unroll
    for (int j=0;j<32;j++) a = fmaf(br[j], q[j], a);
    ws[CQ_OFF + t] = a*scale;
  }
}

// ---- KBD2: fused scores + online chunk softmax + xw chunk partials.
// Block = 64-node chunk processed as 4x 16-node subtiles, each staged ONCE.
// Thread roles: pass1 (sh = wave*8 + (lane>>3), dg = lane&7 slice of 32 d),
// pass2 (thread owns column d=t, acc[32] over sh).
__global__ __launch_bounds__(256,4) void kbd2(const float* __restrict__ x, float* __restrict__ ws){
  int b = blockIdx.x, t = threadIdx.x;
  int c  = (b < 520) ? (b / CPC) : 10;
  int wi = (b < 520) ? (b % CPC) : 0;
  int n0 = c*CS + wi*CPN;
  int n1 = min(n0 + CPN, min((c+1)*CS, N));
  int cnt = n1 - n0;                    // 64, 12 (cluster tail), or 8 (cluster 10)

  __shared__ float xt[16*256];          // 16KB subtile
  __shared__ float sw[16*32];           // scores -> weights in place
  __shared__ float redm[4*32];
  __shared__ float mrun[32], srun[32], fresc[32];

  int wv = t >> 6, lane = t & 63, dg = lane & 7, shw = lane >> 3;
  int sh = wv*8 + shw;
  const float4* WQ4 = (const float4*)(ws + WQ_OFF);
  float4 wqr[8];                        // wq slice, pre-rotated by dg (keeps reg idx static)
#pragma unroll
  for (int q=0;q<8;q++) wqr[q] = WQ4[sh*64 + dg*8 + ((q+dg)&7)];
  float cqr = ws[CQ_OFF + sh];
  const float4* X4 = (const float4*)x;

  if (t < 32){ mrun[t] = -3.0e38f; srun[t] = 0.f; }

  float acc[32];
#pragma unroll
  for (int q=0;q<32;q++) acc[q] = 0.f;

  int jg = t >> 5, sh2 = t & 31;
  int nst = (cnt + 15) >> 4;
  for (int st=0; st<nst; ++st){
    int nb = n0 + st*16;
    int cst = min(16, n1 - nb);
    __syncthreads();                    // protect xt/sw reuse (and mrun init on st=0)
    // stage 16 nodes, coalesced float4
#pragma unroll
    for (int k=0;k<4;k++){
      int f = t + k*256;
      int j = f >> 6, c4 = f & 63;
      int n = nb + j;
      float4 v = (n < n1) ? X4[(size_t)n*64 + c4] : make_float4(0.f,0.f,0.f,0.f);
      *(float4*)(xt + j*256 + c4*4) = v;
    }
    __syncthreads();
    // pass 1: scores via in-wave shfl reduction over dg (lane bits 0-2)
    for (int j=0;j<16;++j){
      const float* xr = xt + j*256 + dg*32;
      float a = 0.f;
#pragma unroll
      for (int q=0;q<8;q++){
        int qq = (q + dg) & 7;          // bank-rotated read order; wqr pre-rotated to match
        float4 xv = *(const float4*)(xr + qq*4);
        a = fmaf(xv.x, wqr[q].x, a); a = fmaf(xv.y, wqr[q].y, a);
        a = fmaf(xv.z, wqr[q].z, a); a = fmaf(xv.w, wqr[q].w, a);
      }
      a += __shfl_xor(a, 1, 64);
      a += __shfl_xor(a, 2, 64);
      a += __shfl_xor(a, 4, 64);
      if (dg == 0) sw[j*32 + sh] = a + cqr;
    }
    __syncthreads();
    // subtile max (masked), merged with running max
    {
      float m = -3.0e38f;
      int j0 = jg*2;
      if (j0     < cst) m = sw[j0*32 + sh2];
      if (j0 + 1 < cst) m = fmaxf(m, sw[(j0+1)*32 + sh2]);
      m = fmaxf(m, __shfl_xor(m, 32, 64));
      if (lane < 32) redm[wv*32 + sh2] = m;
    }
    __syncthreads();
    if (t < 32){
      float mn = fmaxf(fmaxf(redm[t], redm[32+t]), fmaxf(redm[64+t], redm[96+t]));
      mn = fmaxf(mn, mrun[t]);
      fresc[t] = __expf(mrun[t] - mn);  // -inf -> 0 on first subtile (acc is 0 anyway)
      mrun[t] = mn;
    }
    __syncthreads();
    // weights = exp(s - Mnew) in place + subtile sum
    {
      float M = mrun[sh2];
      float ssum = 0.f;
      int j0 = jg*2;
#pragma unroll
      for (int u=0;u<2;u++){
        int j = j0 + u;
        float e = (j < cst) ? __expf(sw[j*32 + sh2] - M) : 0.f;
        sw[j*32 + sh2] = e;
        ssum += e;
      }
      ssum += __shfl_xor(ssum, 32, 64);
      if (lane < 32) redm[wv*32 + sh2] = ssum;
    }
    __syncthreads();
    if (t < 32) srun[t] = srun[t]*fresc[t] + (redm[t]+redm[32+t]+redm[64+t]+redm[96+t]);
    // pass 2: rescale acc, then accumulate this subtile (sw & fresc ready)
#pragma unroll
    for (int q=0;q<32;q++) acc[q] *= fresc[q];
    for (int j=0;j<cst;++j){
      float xv = xt[j*256 + t];
      const float4* W4 = (const float4*)(sw + j*32);
#pragma unroll
      for (int q=0;q<8;q++){
        float4 w = W4[q];
        acc[4*q  ] = fmaf(w.x, xv, acc[4*q  ]);
        acc[4*q+1] = fmaf(w.y, xv, acc[4*q+1]);
        acc[4*q+2] = fmaf(w.z, xv, acc[4*q+2]);
        acc[4*q+3] = fmaf(w.w, xv, acc[4*q+3]);
      }
    }
  }
  __syncthreads();
  if (t < 32){
    ws[PM_OFF + (size_t)b*32 + t] = mrun[t];
    ws[PS_OFF + (size_t)b*32 + t] = srun[t];
  }
  float* pr = ws + PART_OFF + (size_t)b*8192;
#pragma unroll
  for (int q=0;q<32;q++) pr[q*256 + t] = acc[q];
}

// ---- KE2: per-(c,sh) rescaled reduce of chunk partials (kc2 folded in). 352 blocks.
__global__ __launch_bounds__(256) void ke2(float* __restrict__ ws){
  int b = blockIdx.x, t = threadIdx.x;
  int c = b >> 5, sh = b & 31;
  int nch = (c < 10) ? CPC : 1;
  int cb  = (c < 10) ? c*CPC : 520;
  const float* pm = ws + PM_OFF;
  const float* ps = ws + PS_OFF;
  float M = -3.0e38f;
  for (int k=0;k<nch;k++) M = fmaxf(M, pm[(size_t)(cb+k)*32 + sh]);   // block-uniform
  __shared__ float fk[CPC];
  if (t < nch) fk[t] = __expf(pm[(size_t)(cb+t)*32 + sh] - M);
  __syncthreads();
  float S = 0.f;
  for (int k=0;k<nch;k++) S += ps[(size_t)(cb+k)*32 + sh] * fk[k];
  float rden = 1.0f / S;
  const float* part = ws + PART_OFF + (size_t)sh*256 + t;
  float a = 0.f;
  for (int k=0;k<nch;k++) a = fmaf(part[(size_t)(cb+k)*8192], fk[k], a);
  ws[XW_OFF + (size_t)c*8192 + (size_t)sh*256 + t] = a * rden;
}

// ---- KP: pooled[c][s][eq*64..] partial-free (full d, split across dq threads). 176 blocks.
__global__ __launch_bounds__(256) void kp(float* __restrict__ ws,
    const float* __restrict__ Wv, const float* __restrict__ bv){
  int b = blockIdx.x; int c = b >> 4, rem = b & 15, s = rem >> 2, eq = rem & 3;
  int t = threadIdx.x, e64 = t & 63, dq = t >> 6;
  int e = eq*64 + e64, h = e >> 5;
  const float* xr = ws + XW_OFF + (size_t)c*8192 + (size_t)(s*8 + h)*256 + dq*64;
  const float* wv = Wv + (size_t)s*65536 + (size_t)(dq*64)*256 + e;
  float a = 0.f;
#pragma unroll 8
  for (int d=0; d<64; ++d) a = fmaf(wv[(size_t)d*256], xr[d], a);
  __shared__ float red[4][64];
  red[dq][e64] = a;
  __syncthreads();
  if (t < 64){
    float rcnt = (c < 10) ? (1.0f/(float)CS) : 0.125f;
    float p = (red[0][t]+red[1][t]+red[2][t]+red[3][t] + bv[s*256 + eq*64 + t]) * rcnt;
    ws[PL_OFF + (size_t)c*1024 + s*256 + eq*64 + t] = p;
  }
}

// ---- KO: out[c][s][eq*64..] = pooled @ Wo + bo. 176 blocks.
__global__ __launch_bounds__(256) void ko(float* __restrict__ ws,
    const float* __restrict__ Wo, const float* __restrict__ bo){
  int b = blockIdx.x; int c = b >> 4, rem = b & 15, s = rem >> 2, eq = rem & 3;
  int t = threadIdx.x, e64 = t & 63, dq = t >> 6;
  int e = eq*64 + e64;
  const float* pr = ws + PL_OFF + (size_t)c*1024 + s*256 + dq*64;
  const float* wo = Wo + (size_t)s*65536 + (size_t)(dq*64)*256 + e;
  float a = 0.f;
#pragma unroll 8
  for (int d=0; d<64; ++d) a = fmaf(wo[(size_t)d*256], pr[d], a);
  __shared__ float red[4][64];
  red[dq][e64] = a;
  __syncthreads();
  if (t < 64)
    ws[OL_OFF + (size_t)c*1024 + s*256 + eq*64 + t] =
      red[0][t]+red[1][t]+red[2][t]+red[3][t] + bo[s*256 + eq*64 + t];
}

// ---- KF1: h partials: block (c, fq, kq), f-slice 64, k-slice 256. 176 blocks.
__global__ __launch_bounds__(256) void kf1(const float* __restrict__ Wf1, float* __restrict__ ws){
  int b = blockIdx.x; int c = b >> 4, fq = (b >> 2) & 3, kq = b & 3;
  int t = threadIdx.x, f64 = t & 63, ks = t >> 6;
  const float* ol = ws + OL_OFF + (size_t)c*1024 + kq*256 + ks*64;
  const float* wf = Wf1 + (size_t)(kq*256 + ks*64)*256 + fq*64 + f64;
  float a = 0.f;
#pragma unroll 8
  for (int i=0; i<64; ++i) a = fmaf(wf[(size_t)i*256], ol[i], a);
  __shared__ float red[4][64];
  red[ks][f64] = a;
  __syncthreads();
  if (t < 64)
    ws[HP_OFF + (size_t)(c*4 + kq)*256 + fq*64 + t] = red[0][t]+red[1][t]+red[2][t]+red[3][t];
}

// ---- KLN: combine partials + bias -> LayerNorm -> GELU. 11 blocks.
__global__ __launch_bounds__(256) void kln(float* __restrict__ ws, const float* __restrict__ bf1,
    const float* __restrict__ lng, const float* __restrict__ lnb){
  int c = blockIdx.x, t = threadIdx.x;
  __shared__ float rs1[4], rs2[4];
  float hacc = bf1[t];
#pragma unroll
  for (int q=0;q<4;q++) hacc += ws[HP_OFF + (size_t)(c*4+q)*256 + t];
  float s1 = hacc, s2v = hacc*hacc;
  for (int off=32; off>0; off>>=1){ s1 += __shfl_down(s1, off, 64); s2v += __shfl_down(s2v, off, 64); }
  int wid = t>>6, lane = t&63;
  if (lane==0){ rs1[wid]=s1; rs2[wid]=s2v; }
  __syncthreads();
  float S1 = rs1[0]+rs1[1]+rs1[2]+rs1[3];
  float S2 = rs2[0]+rs2[1]+rs2[2]+rs2[3];
  float mu = S1*(1.0f/256.0f);
  float var = S2*(1.0f/256.0f) - mu*mu;
  float rsig = rsqrtf(var + 1e-5f);
  float hn = (hacc - mu)*rsig*lng[t] + lnb[t];
  float ge = 0.5f*hn*(1.0f + erff(hn*0.70710678118654752f));   // exact GELU
  ws[HL_OFF + (size_t)c*256 + t] = ge;
}

// ---- KF2: f2 partials: block (c, gq, kq), g-slice 64, k-slice 64. 176 blocks.
__global__ __launch_bounds__(256) void kf2(const float* __restrict__ Wf2, float* __restrict__ ws){
  int b = blockIdx.x; int c = b >> 4, gq = (b >> 2) & 3, kq = b & 3;
  int t = threadIdx.x, g64 = t & 63, ks = t >> 6;
  const float* hp = ws + HL_OFF + (size_t)c*256 + kq*64 + ks*16;
  const float* wf = Wf2 + (size_t)(kq*64 + ks*16)*256 + gq*64 + g64;
  float a = 0.f;
#pragma unroll
  for (int i=0; i<16; ++i) a = fmaf(wf[(size_t)i*256], hp[i], a);
  __shared__ float red[4][64];
  red[ks][g64] = a;
  __syncthreads();
  if (t < 64)
    ws[FP_OFF + (size_t)(c*4 + kq)*256 + gq*64 + t] = red[0][t]+red[1][t]+red[2][t]+red[3][t];
}

// ---- KBC2: sum Wf2 partials + bf2 once per block, broadcast to nodes. 8192 blocks.
// 3276 % 4 == 0 so each 4-node block lies in exactly one cluster.
__global__ __launch_bounds__(256) void kbc2(const float* __restrict__ ws, float4* __restrict__ out,
                                            const float* __restrict__ bf2){
  unsigned bidx = blockIdx.x, t = threadIdx.x;
  unsigned idx = bidx*256u + t;
  unsigned c = (bidx*4u) / (unsigned)CS;
  __shared__ float4 row[64];
  if (t < 64){
    const float4* FP4 = (const float4*)(ws + FP_OFF);
    float4 s0 = FP4[(c*4+0)*64 + t];
    float4 s1 = FP4[(c*4+1)*64 + t];
    float4 s2 = FP4[(c*4+2)*64 + t];
    float4 s3 = FP4[(c*4+3)*64 + t];
    float4 bb = ((const float4*)bf2)[t];
    row[t] = make_float4(s0.x+s1.x+s2.x+s3.x+bb.x, s0.y+s1.y+s2.y+s3.y+bb.y,
                         s0.z+s1.z+s2.z+s3.z+bb.z, s0.w+s1.w+s2.w+s3.w+bb.w);
  }
  __syncthreads();
  out[idx] = row[t & 63u];
}

extern "C" void kernel_launch(void* const* d_in, const int* in_sizes, int n_in,
                              void* d_out, int out_size, void* d_ws, size_t ws_size,
                              hipStream_t stream) {
  const float* x   = (const float*)d_in[0];
  // d_in[1] edge_index, d_in[2] batch: unused by the reference computation
  const float* Wk  = (const float*)d_in[3];
  const float* bk  = (const float*)d_in[4];
  const float* Wv  = (const float*)d_in[5];
  const float* bv  = (const float*)d_in[6];
  const float* Wo  = (const float*)d_in[7];
  const float* bo  = (const float*)d_in[8];
  const float* pq  = (const float*)d_in[9];
  const float* Wf1 = (const float*)d_in[10];
  const float* bf1 = (const float*)d_in[11];
  const float* lng = (const float*)d_in[12];
  const float* lnb = (const float*)d_in[13];
  const float* Wf2 = (const float*)d_in[14];
  const float* bf2 = (const float*)d_in[15];
  float* ws = (float*)d_ws;
  float4* out = (float4*)d_out;

  hipLaunchKernelGGL(ka,   dim3(33),   dim3(256), 0, stream, Wk, bk, pq, ws);
  hipLaunchKernelGGL(kbd2, dim3(NB),   dim3(256), 0, stream, x, ws);
  hipLaunchKernelGGL(ke2,  dim3(352),  dim3(256), 0, stream, ws);
  hipLaunchKernelGGL(kp,   dim3(176),  dim3(256), 0, stream, ws, Wv, bv);
  hipLaunchKernelGGL(ko,   dim3(176),  dim3(256), 0, stream, ws, Wo, bo);
  hipLaunchKernelGGL(kf1,  dim3(176),  dim3(256), 0, stream, Wf1, ws);
  hipLaunchKernelGGL(kln,  dim3(11),   dim3(256), 0, stream, ws, bf1, lng, lnb);
  hipLaunchKernelGGL(kf2,  dim3(176),  dim3(256), 0, stream, Wf2, ws);
  hipLaunchKernelGGL(kbc2, dim3(8192), dim3(256), 0, stream, ws, out, bf2);
}